// Round 29
// baseline (28.436 us; speedup 1.0000x reference)
//
#include <hip/hip_runtime.h>

// GaussianAntecedent: out[n,r] = mem[n,r] / (sum_r mem[n,r] + 1e-8)
// mem = exp2( -sum_d clamp(q*x+pn, +-K)^2 ),  K = sqrt(-log2(1e-8))
//   q = sqrt(0.5*log2 e)/(sigma+eps), pn = -c*q
//
// R28 post-mortem: occupancy not the lever (28.4, bf16 tile kept: absmax
// 4.7e-10, 550x margin). Last untried structural stall: read->use
// serialization of per-rule constant loads (R20's VGPR=52 = tiny sched
// window; R23's within-rule pin made no CROSS-phase overlap). R29:
// explicit SOFTWARE PIPELINE at half-rule granularity -- while computing
// half h from buffer A, the 8 ds_read_b128 of the next half stream into
// buffer B. Static names b0/b1 (no pointer selection, rule-#20 safe).
// launch_bounds(256,3): ~154 VGPR fits; grid is 3.05 blocks/CU anyway.

typedef float v2f __attribute__((ext_vector_type(2)));

constexpr int DDIM = 32;
constexpr int RR   = 64;
constexpr int ROWS = 128;   // rows per block (2 per lane)
constexpr int PP   = 5;     // partials pitch (floats)
constexpr int XP   = 33;    // X stage pitch (floats)
constexpr int MPH  = 130;   // mem tile pitch (ushorts); word-pitch 65 (odd)

__device__ inline float fast_exp2(float x) {
#if __has_builtin(__builtin_amdgcn_exp2f)
    return __builtin_amdgcn_exp2f(x);
#else
    return exp2f(x);
#endif
}

__device__ inline unsigned short f2bf(float x) {
    return (unsigned short)((__float_as_uint(x) + 0x8000u) >> 16);
}
__device__ inline float bf2f(unsigned short h) {
    return __uint_as_float(((unsigned int)h) << 16);
}

__global__ __launch_bounds__(256, 3) void gauss_main(
    const float* __restrict__ X,
    const float* __restrict__ centers,
    const float* __restrict__ sigma,
    float* __restrict__ out, int N)
{
    __shared__ float tabL[RR * 64];        // 16 KB   [rule]{q[32]|pn[32]}
    __shared__ float bufL[ROWS * XP];      // 16.9 KB: xsL then memH (alias)
    __shared__ float partL[ROWS * PP];     // 2.56 KB [row][wave]
    __shared__ float rsL[ROWS];            // 0.5 KB  rcp(S) per row
    float* xsL = bufL;                             // [128][33] staged X
    unsigned short* memH = (unsigned short*)bufL;  // [64][130] bf16 mem

    const int tid  = threadIdx.x;
    const int lane = tid & 63;
    const int w    = tid >> 6;
    const int n0   = blockIdx.x * ROWS;

    // ---- coalesced X loads: 4 float4/thread, linear over the 16KB tile ----
    float4 xg[4];
    #pragma unroll
    for (int k = 0; k < 4; ++k) {
        const int f   = k * 256 + tid;       // float4 index 0..1023
        const int row = f >> 3;              // 0..127
        const int col = (f & 7) * 4;         // 0..28
        int rsrc = n0 + row; if (rsrc >= N) rsrc = N - 1;
        xg[k] = *reinterpret_cast<const float4*>(X + (size_t)rsrc * DDIM + col);
    }

    // ---- build q/pn table in LDS (rcpf: no slow f32 divide) ----
    const float SQK = 0.84932180028801907f;   // sqrt(0.5 * log2(e))
    #pragma unroll
    for (int i = 0; i < 8; ++i) {
        const int pi = tid * 8 + i;           // (rule, dim) pair 0..2047
        const int r  = pi >> 5, d = pi & 31;
        float q  = SQK * __builtin_amdgcn_rcpf(sigma[r * DDIM + d] + 1e-8f);
        tabL[r * 64 + d]        = q;
        tabL[r * 64 + DDIM + d] = -centers[r * DDIM + d] * q;
    }

    // ---- write staged X into xsL (pitch 33) ----
    #pragma unroll
    for (int k = 0; k < 4; ++k) {
        const int f   = k * 256 + tid;
        const int row = f >> 3;
        const int col = (f & 7) * 4;
        xsL[row * XP + col + 0] = xg[k].x;
        xsL[row * XP + col + 1] = xg[k].y;
        xsL[row * XP + col + 2] = xg[k].z;
        xsL[row * XP + col + 3] = xg[k].w;
    }
    __syncthreads();   // bar1: xsL + tabL ready

    // ---- own 2 rows -> registers ----
    v2f xa2[16], xb2[16];
    #pragma unroll
    for (int p = 0; p < 16; ++p) {
        xa2[p] = (v2f){xsL[lane * XP + 2 * p], xsL[lane * XP + 2 * p + 1]};
        xb2[p] = (v2f){xsL[(64 + lane) * XP + 2 * p],
                       xsL[(64 + lane) * XP + 2 * p + 1]};
    }
    __syncthreads();   // bar2: xsL dead; memH may now be written

    const float K = 5.1551357f;   // sqrt(26.575424759098897) = sqrt(-log2 1e-8)
    const int rbase = w * 16;
    float Sa = 0.f, Sb = 0.f;

    // half-rule constant buffers: q quads then pn quads (8 float4 = 32 regs)
    float4 b0[8], b1[8];

    // LOADH: half h of rule r -> buf
    #define LOADH(buf, r, h)                                                  \
        {                                                                     \
            const float4* __restrict__ tp_ =                                  \
                reinterpret_cast<const float4*>(&tabL[(r) * 64]);             \
            _Pragma("unroll")                                                 \
            for (int k_ = 0; k_ < 4; ++k_) {                                  \
                buf[k_]     = tp_[4 * (h) + k_];                              \
                buf[4 + k_] = tp_[8 + 4 * (h) + k_];                          \
            }                                                                 \
        }

    // COMPUTE: half h from buf into Aa/Ab (96 VALU ops)
    #define COMPUTE(buf, h)                                                   \
        {                                                                     \
            _Pragma("unroll")                                                 \
            for (int j_ = 0; j_ < 4; ++j_) {                                  \
                float4 qf = buf[j_], pf = buf[4 + j_];                        \
                v2f q0 = {qf.x, qf.y}, q1 = {qf.z, qf.w};                     \
                v2f p0 = {pf.x, pf.y}, p1 = {pf.z, pf.w};                     \
                const int jj = 8 * (h) + 2 * j_;                              \
                v2f ta0 = __builtin_elementwise_fma(q0, xa2[jj],     p0);     \
                v2f ta1 = __builtin_elementwise_fma(q1, xa2[jj + 1], p1);     \
                v2f tb0 = __builtin_elementwise_fma(q0, xb2[jj],     p0);     \
                v2f tb1 = __builtin_elementwise_fma(q1, xb2[jj + 1], p1);     \
                ta0.x = fminf(fmaxf(ta0.x, -K), K);                           \
                ta0.y = fminf(fmaxf(ta0.y, -K), K);                           \
                ta1.x = fminf(fmaxf(ta1.x, -K), K);                           \
                ta1.y = fminf(fmaxf(ta1.y, -K), K);                           \
                tb0.x = fminf(fmaxf(tb0.x, -K), K);                           \
                tb0.y = fminf(fmaxf(tb0.y, -K), K);                           \
                tb1.x = fminf(fmaxf(tb1.x, -K), K);                           \
                tb1.y = fminf(fmaxf(tb1.y, -K), K);                           \
                Aa[0] = __builtin_elementwise_fma(ta0, -ta0, Aa[0]);          \
                Aa[1] = __builtin_elementwise_fma(ta1, -ta1, Aa[1]);          \
                Ab[0] = __builtin_elementwise_fma(tb0, -tb0, Ab[0]);          \
                Ab[1] = __builtin_elementwise_fma(tb1, -tb1, Ab[1]);          \
            }                                                                 \
        }

    LOADH(b0, rbase, 0);   // prologue: first half in flight

    #pragma unroll
    for (int rr = 0; rr < 16; ++rr) {
        const int r = rbase + rr;
        v2f Aa[2] = {{0.f,0.f},{0.f,0.f}};
        v2f Ab[2] = {{0.f,0.f},{0.f,0.f}};

        LOADH(b1, r, 1);          // h1 reads stream under h0 compute
        COMPUTE(b0, 0);
        if (rr < 15) LOADH(b0, r + 1, 0);   // next rule h0 under h1 compute
        COMPUTE(b1, 1);

        v2f aa = Aa[0] + Aa[1];
        v2f ab = Ab[0] + Ab[1];
        float ma = fast_exp2(aa.x + aa.y);
        float mb = fast_exp2(ab.x + ab.y);
        Sa += ma;
        Sb += mb;
        memH[r * MPH + lane]      = f2bf(ma);   // 2B stride-1: 2-way, free
        memH[r * MPH + 64 + lane] = f2bf(mb);
    }
    #undef LOADH
    #undef COMPUTE

    partL[lane * PP + w]        = Sa;    // (5*lane+w)%32: 2-way, free
    partL[(64 + lane) * PP + w] = Sb;

    __syncthreads();   // bar3: mem tile + partials ready

    if (tid < ROWS) {
        float s = partL[tid * PP + 0] + partL[tid * PP + 1] +
                  partL[tid * PP + 2] + partL[tid * PP + 3];
        rsL[tid] = __builtin_amdgcn_rcpf(s + 1e-8f);
    }
    __syncthreads();   // bar4: rs ready

    // ---- epilogue: contiguous 4KB-per-step float4 stores ----
    const int nvalid = N - n0;   // rows in this block (128 except last)
    #pragma unroll
    for (int ch = 0; ch < 8; ++ch) {
        const int f4  = ch * 256 + tid;       // 0..2047
        const int row = f4 >> 4;              // 0..127
        const int r4  = (f4 & 15) * 4;        // rule quad base
        if (row < nvalid) {
            float rs = rsL[row];
            float4 o;
            o.x = bf2f(memH[(r4 + 0) * MPH + row]) * rs;
            o.y = bf2f(memH[(r4 + 1) * MPH + row]) * rs;
            o.z = bf2f(memH[(r4 + 2) * MPH + row]) * rs;
            o.w = bf2f(memH[(r4 + 3) * MPH + row]) * rs;
            *reinterpret_cast<float4*>(&out[(size_t)(n0 + row) * RR + r4]) = o;
        }
    }
}

extern "C" void kernel_launch(void* const* d_in, const int* in_sizes, int n_in,
                              void* d_out, int out_size, void* d_ws, size_t ws_size,
                              hipStream_t stream) {
    const float* X       = (const float*)d_in[0];
    const float* centers = (const float*)d_in[1];
    const float* sigma   = (const float*)d_in[2];
    float* out = (float*)d_out;

    const int N = in_sizes[0] / DDIM;  // 100000
    const int grid = (N + ROWS - 1) / ROWS;   // 782
    gauss_main<<<grid, 256, 0, stream>>>(X, centers, sigma, out, N);
}